// Round 7
// baseline (293.987 us; speedup 1.0000x reference)
//
#include <hip/hip_runtime.h>
#include <hip/hip_fp16.h>

#define N_NODES  50000
#define N_EDGES  300000
#define IN_FEATS 1433
#define HIDDEN   16
#define OUT_F    7
#define KPAD     1472   // 23*64, zero-padded K extent for W1 in LDS
#define WROW     9      // dwords per W1 row in LDS (stride 9 -> conflict-free b128 reads)
#define NCHUNK   (N_NODES / 4)   // 12500 four-row chunks

// ---------- Kernel 1: H = F @ W1 (fp16 W in LDS); aggbuf = H + b1 ----------
// 512-thr blocks, 3 blocks/CU -> 24 waves/CU (VGPR cap). Work-stealing chunk
// dispatch: lane0 atomicAdd on global counter -> perfect load balance.
__global__ __launch_bounds__(512) void k1_gemm(
    const float* __restrict__ F, const float* __restrict__ W1,
    const float* __restrict__ b1, __half* __restrict__ H,
    __half* __restrict__ aggbuf, unsigned int* __restrict__ ctr)
{
    __shared__ unsigned int Wl[KPAD * WROW];   // 52,992 B -> 3 blocks/CU
    const int tid = threadIdx.x;

    // Stage W1 as packed fp16 pairs (RNE), zero-padded rows [1433, KPAD)
    for (int idx = tid; idx < KPAD * 8; idx += 512) {
        int k = idx >> 3, c = idx & 7;
        unsigned int u = 0u;
        if (k < IN_FEATS) {
            __half2 h2 = __floats2half2_rn(W1[k * 16 + 2 * c], W1[k * 16 + 2 * c + 1]);
            u = *reinterpret_cast<unsigned int*>(&h2);
        }
        Wl[k * WROW + c] = u;
    }
    __syncthreads();

    const int lane = tid & 63;
    const float b1v = b1[lane & 15];

    for (;;) {
        int ch;
        if (lane == 0) ch = (int)atomicAdd(ctr, 1u);
        ch = __shfl(ch, 0, 64);
        if (ch >= NCHUNK) break;

        const int r0 = ch * 4;
        const float* fp = F + (size_t)r0 * IN_FEATS;

        float v[64];                                    // acc[idx = r*16 + j]
        #pragma unroll
        for (int i = 0; i < 64; ++i) v[i] = 0.f;

        #pragma unroll 2
        for (int i = 0; i < 22; ++i) {          // k < 1408: no bounds check
            const int k = i * 64 + lane;
            const float f0 = fp[k];
            const float f1 = fp[IN_FEATS + k];
            const float f2 = fp[2 * IN_FEATS + k];
            const float f3 = fp[3 * IN_FEATS + k];
            float wv[16];
            #pragma unroll
            for (int c = 0; c < 8; ++c) {
                unsigned int u = Wl[k * WROW + c];
                __half2 h2 = *reinterpret_cast<__half2*>(&u);
                float2 f = __half22float2(h2);
                wv[2 * c]     = f.x;
                wv[2 * c + 1] = f.y;
            }
            #pragma unroll
            for (int j = 0; j < 16; ++j) {
                v[j]      += f0 * wv[j];
                v[16 + j] += f1 * wv[j];
                v[32 + j] += f2 * wv[j];
                v[48 + j] += f3 * wv[j];
            }
        }
        {   // masked tail: k = 1408 + lane
            const int k = 1408 + lane;
            float f0 = 0.f, f1 = 0.f, f2 = 0.f, f3 = 0.f;
            if (k < IN_FEATS) {
                f0 = fp[k];
                f1 = fp[IN_FEATS + k];
                f2 = fp[2 * IN_FEATS + k];
                f3 = fp[3 * IN_FEATS + k];
            }
            float wv[16];
            #pragma unroll
            for (int c = 0; c < 8; ++c) {
                unsigned int u = Wl[k * WROW + c];   // zero-padded rows
                __half2 h2 = *reinterpret_cast<__half2*>(&u);
                float2 f = __half22float2(h2);
                wv[2 * c]     = f.x;
                wv[2 * c + 1] = f.y;
            }
            #pragma unroll
            for (int j = 0; j < 16; ++j) {
                v[j]      += f0 * wv[j];
                v[16 + j] += f1 * wv[j];
                v[32 + j] += f2 * wv[j];
                v[48 + j] += f3 * wv[j];
            }
        }

        // Halving butterfly: lane l ends with v[0] = full K-sum of idx = l
        #pragma unroll
        for (int d = 5; d >= 0; --d) {
            const int half = 1 << d;
            const bool hi = (lane >> d) & 1;
            #pragma unroll
            for (int t = 0; t < (1 << d); ++t) {
                float sent = hi ? v[t] : v[t + half];
                float recv = __shfl_xor(sent, half, 64);
                float keep = hi ? v[t + half] : v[t];
                v[t] = keep + recv;
            }
        }
        const size_t off = (size_t)r0 * 16 + lane;
        H[off]      = __float2half(v[0]);
        aggbuf[off] = __float2half(v[0] + b1v);
    }
}

// ---------- Kernel 2: aggbuf[dst] += H[src], packed-fp16 atomics ----------
__global__ __launch_bounds__(256) void k2_scatter1(
    const int* __restrict__ src, const int* __restrict__ dst,
    const __half2* __restrict__ H2, __half2* __restrict__ agg2)
{
    int t = blockIdx.x * 256 + threadIdx.x;     // grid sized exactly N_EDGES*8
    int e = t >> 3, p = t & 7;
    int s = src[e], d = dst[e];
    __half2 val = H2[(size_t)s * 8 + p];
    unsafeAtomicAdd(&agg2[(size_t)d * 8 + p], val);   // global_atomic_pk_add_f16
}

// ---------- Kernel 3: x = relu(aggbuf fp16); G = x @ W2; out = G + b2 ----------
__global__ __launch_bounds__(256) void k3_layer2(
    const __half2* __restrict__ agg2, const float* __restrict__ W2,
    const float* __restrict__ b2, float* __restrict__ G,
    float* __restrict__ out)
{
    int n = blockIdx.x * 256 + threadIdx.x;
    if (n >= N_NODES) return;
    float x[16];
    #pragma unroll
    for (int p = 0; p < 8; ++p) {
        float2 f = __half22float2(agg2[(size_t)n * 8 + p]);
        x[2 * p]     = f.x > 0.f ? f.x : 0.f;
        x[2 * p + 1] = f.y > 0.f ? f.y : 0.f;
    }
    #pragma unroll
    for (int j = 0; j < OUT_F; ++j) {
        float g = 0.f;
        #pragma unroll
        for (int k = 0; k < 16; ++k) g += x[k] * W2[k * OUT_F + j];
        G[(size_t)n * OUT_F + j] = g;
        out[(size_t)n * OUT_F + j] = g + b2[j];
    }
}

// ---------- Kernel 4: out[dst] += G[src], f32 atomics ----------
__global__ __launch_bounds__(256) void k4_scatter2(
    const int* __restrict__ src, const int* __restrict__ dst,
    const float* __restrict__ G, float* __restrict__ out)
{
    int t = blockIdx.x * 256 + threadIdx.x;
    int e = t / OUT_F, j = t % OUT_F;
    if (e < N_EDGES) {
        atomicAdd(&out[(size_t)dst[e] * OUT_F + j], G[(size_t)src[e] * OUT_F + j]);
    }
}

extern "C" void kernel_launch(void* const* d_in, const int* in_sizes, int n_in,
                              void* d_out, int out_size, void* d_ws, size_t ws_size,
                              hipStream_t stream)
{
    const float* F   = (const float*)d_in[0];
    const int*   src = (const int*)d_in[1];
    const int*   dst = (const int*)d_in[2];
    const float* W1  = (const float*)d_in[3];
    const float* b1  = (const float*)d_in[4];
    const float* W2  = (const float*)d_in[5];
    const float* b2  = (const float*)d_in[6];
    float* out = (float*)d_out;

    __half* H      = (__half*)d_ws;                         // 800,000 fp16 (1.6 MB)
    __half* aggbuf = H + (size_t)N_NODES * HIDDEN;          // 800,000 fp16 (1.6 MB)
    float*  G      = (float*)(aggbuf + (size_t)N_NODES * HIDDEN);  // 350,000 f32
    unsigned int* ctr = (unsigned int*)(G + (size_t)N_NODES * OUT_F);

    hipMemsetAsync(ctr, 0, sizeof(unsigned int), stream);

    // 768 blocks x 512 thr = 3 blocks/CU, 24 waves/CU (VGPR-cap occupancy)
    k1_gemm<<<768, 512, 0, stream>>>(F, W1, b1, H, aggbuf, ctr);
    k2_scatter1<<<(N_EDGES * 8) / 256, 256, 0, stream>>>(src, dst,
        (const __half2*)H, (__half2*)aggbuf);
    k3_layer2<<<(N_NODES + 255) / 256, 256, 0, stream>>>((const __half2*)aggbuf,
        W2, b2, G, out);
    k4_scatter2<<<(N_EDGES * OUT_F + 255) / 256, 256, 0, stream>>>(src, dst, G, out);
}

// Round 8
// 138.378 us; speedup vs baseline: 2.1245x; 2.1245x over previous
//
#include <hip/hip_runtime.h>
#include <hip/hip_fp16.h>

#define N_NODES  50000
#define N_EDGES  300000
#define IN_FEATS 1433
#define HIDDEN   16
#define OUT_F    7
#define KPAD     1472    // 23*64 = 4*368, zero-padded K extent for W1 in LDS
#define SUBSZ    3312    // 368 rows * 9 dwords per sub-array
// LDS layout: 4 sub-arrays by (k&3); row (k>>2), stride 9 dwords, 8 used.
// Vector phase: all lanes read sub-array q at row 64i+lane -> dword 9*lane apart
// -> 9 odd -> 32 distinct banks over 32 lanes -> 2 lanes/bank = conflict-free.
#define WOFF(k, c) (((k) & 3) * SUBSZ + ((k) >> 2) * 9 + (c))

// ---------- Kernel 1: H = F @ W1 (fp16 W in LDS); aggbuf = H + b1 ----------
// float4 F loads: 4KB/wave in flight per step (vs 256B scalar) -> latency hidden.
__global__ __launch_bounds__(256, 3) void k1_gemm(
    const float* __restrict__ F, const float* __restrict__ W1,
    const float* __restrict__ b1, __half* __restrict__ H,
    __half* __restrict__ aggbuf)
{
    __shared__ unsigned int Wl[4 * SUBSZ];   // 52,992 B -> 3 blocks/CU
    const int tid = threadIdx.x;

    // Stage W1 as packed fp16 pairs (RNE), zero rows for k in [1433, KPAD)
    for (int idx = tid; idx < KPAD * 8; idx += 256) {
        int k = idx >> 3, c = idx & 7;
        unsigned int u = 0u;
        if (k < IN_FEATS) {
            __half2 h2 = __floats2half2_rn(W1[k * 16 + 2 * c], W1[k * 16 + 2 * c + 1]);
            u = *reinterpret_cast<unsigned int*>(&h2);
        }
        Wl[WOFF(k, c)] = u;
    }
    __syncthreads();

    const int lane = tid & 63;
    const float b1v = b1[lane & 15];
    const int gwave  = blockIdx.x * 4 + (tid >> 6);
    const int nwaves = gridDim.x * 4;

    for (int ch = gwave; ch < N_NODES / 4; ch += nwaves) {
        const int r0 = ch * 4;
        const float* fp = F + (size_t)r0 * IN_FEATS;

        float v[64];                                    // acc[idx = r*16 + j]
        #pragma unroll
        for (int i = 0; i < 64; ++i) v[i] = 0.f;

        // 5 full float4 iters: cols 0..1279 (256 cols/iter, 1KB/row coalesced)
        #pragma unroll 2
        for (int i = 0; i < 5; ++i) {
            const int k0 = i * 256 + 4 * lane;
            const float4 f0 = *reinterpret_cast<const float4*>(fp + k0);
            const float4 f1 = *reinterpret_cast<const float4*>(fp + IN_FEATS + k0);
            const float4 f2 = *reinterpret_cast<const float4*>(fp + 2 * IN_FEATS + k0);
            const float4 f3 = *reinterpret_cast<const float4*>(fp + 3 * IN_FEATS + k0);
            const int rr = i * 64 + lane;               // = k0 >> 2
            #pragma unroll
            for (int q = 0; q < 4; ++q) {
                float wv[16];
                #pragma unroll
                for (int c = 0; c < 8; ++c) {
                    unsigned int u = Wl[q * SUBSZ + rr * 9 + c];
                    __half2 h2 = *reinterpret_cast<__half2*>(&u);
                    float2 f = __half22float2(h2);
                    wv[2 * c]     = f.x;
                    wv[2 * c + 1] = f.y;
                }
                const float a0 = (&f0.x)[q], a1 = (&f1.x)[q];
                const float a2 = (&f2.x)[q], a3 = (&f3.x)[q];
                #pragma unroll
                for (int j = 0; j < 16; ++j) {
                    v[j]      += a0 * wv[j];
                    v[16 + j] += a1 * wv[j];
                    v[32 + j] += a2 * wv[j];
                    v[48 + j] += a3 * wv[j];
                }
            }
        }
        // Half iter: cols 1280..1407 (32 float4, lanes 0..31)
        if (lane < 32) {
            const int k0 = 1280 + 4 * lane;
            const float4 f0 = *reinterpret_cast<const float4*>(fp + k0);
            const float4 f1 = *reinterpret_cast<const float4*>(fp + IN_FEATS + k0);
            const float4 f2 = *reinterpret_cast<const float4*>(fp + 2 * IN_FEATS + k0);
            const float4 f3 = *reinterpret_cast<const float4*>(fp + 3 * IN_FEATS + k0);
            const int rr = 320 + lane;
            #pragma unroll
            for (int q = 0; q < 4; ++q) {
                float wv[16];
                #pragma unroll
                for (int c = 0; c < 8; ++c) {
                    unsigned int u = Wl[q * SUBSZ + rr * 9 + c];
                    __half2 h2 = *reinterpret_cast<__half2*>(&u);
                    float2 f = __half22float2(h2);
                    wv[2 * c]     = f.x;
                    wv[2 * c + 1] = f.y;
                }
                const float a0 = (&f0.x)[q], a1 = (&f1.x)[q];
                const float a2 = (&f2.x)[q], a3 = (&f3.x)[q];
                #pragma unroll
                for (int j = 0; j < 16; ++j) {
                    v[j]      += a0 * wv[j];
                    v[16 + j] += a1 * wv[j];
                    v[32 + j] += a2 * wv[j];
                    v[48 + j] += a3 * wv[j];
                }
            }
        }
        // Scalar tail: k = 1408 + lane, active lanes k < 1433
        {
            const int k = 1408 + lane;
            float f0 = 0.f, f1 = 0.f, f2 = 0.f, f3 = 0.f;
            if (k < IN_FEATS) {
                f0 = fp[k];
                f1 = fp[IN_FEATS + k];
                f2 = fp[2 * IN_FEATS + k];
                f3 = fp[3 * IN_FEATS + k];
            }
            float wv[16];
            #pragma unroll
            for (int c = 0; c < 8; ++c) {
                unsigned int u = Wl[WOFF(k, c)];        // zero rows k >= 1433
                __half2 h2 = *reinterpret_cast<__half2*>(&u);
                float2 f = __half22float2(h2);
                wv[2 * c]     = f.x;
                wv[2 * c + 1] = f.y;
            }
            #pragma unroll
            for (int j = 0; j < 16; ++j) {
                v[j]      += f0 * wv[j];
                v[16 + j] += f1 * wv[j];
                v[32 + j] += f2 * wv[j];
                v[48 + j] += f3 * wv[j];
            }
        }

        // Halving butterfly: lane l ends with v[0] = full K-sum of idx = l
        #pragma unroll
        for (int d = 5; d >= 0; --d) {
            const int half = 1 << d;
            const bool hi = (lane >> d) & 1;
            #pragma unroll
            for (int t = 0; t < (1 << d); ++t) {
                float sent = hi ? v[t] : v[t + half];
                float recv = __shfl_xor(sent, half, 64);
                float keep = hi ? v[t + half] : v[t];
                v[t] = keep + recv;
            }
        }
        const size_t off = (size_t)r0 * 16 + lane;
        H[off]      = __float2half(v[0]);
        aggbuf[off] = __float2half(v[0] + b1v);
    }
}

// ---------- Kernel 2: aggbuf[dst] += H[src], packed-fp16 atomics ----------
__global__ __launch_bounds__(256) void k2_scatter1(
    const int* __restrict__ src, const int* __restrict__ dst,
    const __half2* __restrict__ H2, __half2* __restrict__ agg2)
{
    int t = blockIdx.x * 256 + threadIdx.x;     // grid sized exactly N_EDGES*8
    int e = t >> 3, p = t & 7;
    int s = src[e], d = dst[e];
    __half2 val = H2[(size_t)s * 8 + p];
    unsafeAtomicAdd(&agg2[(size_t)d * 8 + p], val);   // global_atomic_pk_add_f16
}

// ---------- Kernel 3: x = relu(aggbuf fp16); G = x @ W2; out = G + b2 ----------
__global__ __launch_bounds__(256) void k3_layer2(
    const __half2* __restrict__ agg2, const float* __restrict__ W2,
    const float* __restrict__ b2, float* __restrict__ G,
    float* __restrict__ out)
{
    int n = blockIdx.x * 256 + threadIdx.x;
    if (n >= N_NODES) return;
    float x[16];
    #pragma unroll
    for (int p = 0; p < 8; ++p) {
        float2 f = __half22float2(agg2[(size_t)n * 8 + p]);
        x[2 * p]     = f.x > 0.f ? f.x : 0.f;
        x[2 * p + 1] = f.y > 0.f ? f.y : 0.f;
    }
    #pragma unroll
    for (int j = 0; j < OUT_F; ++j) {
        float g = 0.f;
        #pragma unroll
        for (int k = 0; k < 16; ++k) g += x[k] * W2[k * OUT_F + j];
        G[(size_t)n * OUT_F + j] = g;
        out[(size_t)n * OUT_F + j] = g + b2[j];
    }
}

// ---------- Kernel 4: out[dst] += G[src], f32 atomics ----------
__global__ __launch_bounds__(256) void k4_scatter2(
    const int* __restrict__ src, const int* __restrict__ dst,
    const float* __restrict__ G, float* __restrict__ out)
{
    int t = blockIdx.x * 256 + threadIdx.x;
    int e = t / OUT_F, j = t % OUT_F;
    if (e < N_EDGES) {
        atomicAdd(&out[(size_t)dst[e] * OUT_F + j], G[(size_t)src[e] * OUT_F + j]);
    }
}

extern "C" void kernel_launch(void* const* d_in, const int* in_sizes, int n_in,
                              void* d_out, int out_size, void* d_ws, size_t ws_size,
                              hipStream_t stream)
{
    const float* F   = (const float*)d_in[0];
    const int*   src = (const int*)d_in[1];
    const int*   dst = (const int*)d_in[2];
    const float* W1  = (const float*)d_in[3];
    const float* b1  = (const float*)d_in[4];
    const float* W2  = (const float*)d_in[5];
    const float* b2  = (const float*)d_in[6];
    float* out = (float*)d_out;

    __half* H      = (__half*)d_ws;                         // 800,000 fp16 (1.6 MB)
    __half* aggbuf = H + (size_t)N_NODES * HIDDEN;          // 800,000 fp16 (1.6 MB)
    float*  G      = (float*)(aggbuf + (size_t)N_NODES * HIDDEN);  // 350,000 f32

    // 768 blocks x 256 thr = 3 blocks/CU (LDS-capped), per-wave grid-stride
    k1_gemm<<<768, 256, 0, stream>>>(F, W1, b1, H, aggbuf);
    k2_scatter1<<<(N_EDGES * 8) / 256, 256, 0, stream>>>(src, dst,
        (const __half2*)H, (__half2*)aggbuf);
    k3_layer2<<<(N_NODES + 255) / 256, 256, 0, stream>>>((const __half2*)aggbuf,
        W2, b2, G, out);
    k4_scatter2<<<(N_EDGES * OUT_F + 255) / 256, 256, 0, stream>>>(src, dst, G, out);
}